// Round 1
// baseline (2046.595 us; speedup 1.0000x reference)
//
#include <hip/hip_runtime.h>
#include <math.h>

// SE (RBF) kernel attention: B=2, H=16, S=2048, D=64, fp32 in/out.
// score = (k2 - sqrt(max(q2 - 2 q.k + k2, 0))) / 16   (q2 additive term
// cancels in softmax). Flash-style online softmax, fp32 vector math.
#define BH   32
#define SEQ  2048
#define DIM  64
#define D4   16      // DIM/4
#define QB   64      // queries per block (== wave)
#define KB   64      // keys per LDS tile
#define NKT  (SEQ / KB)

__global__ __launch_bounds__(64)
void se_attn_fp32(const float* __restrict__ Qg, const float* __restrict__ Kg,
                  const float* __restrict__ Vg, float* __restrict__ Og) {
    __shared__ float4 Ks[KB * D4];
    __shared__ float4 Vs[KB * D4];
    __shared__ float  k2s[KB];

    const int t    = threadIdx.x;        // 0..63, one query per lane
    const int head = blockIdx.y;         // 0..31
    const int q    = blockIdx.x * QB + t;

    const size_t hbase = (size_t)head * SEQ * DIM;

    // Load this lane's query row into registers; compute q2.
    const float4* qp = (const float4*)(Qg + hbase + (size_t)q * DIM);
    float4 qr[D4];
    float  q2 = 0.f;
#pragma unroll
    for (int j = 0; j < D4; ++j) {
        qr[j] = qp[j];
        q2 += qr[j].x * qr[j].x + qr[j].y * qr[j].y +
              qr[j].z * qr[j].z + qr[j].w * qr[j].w;
    }

    float4 o[D4];
#pragma unroll
    for (int j = 0; j < D4; ++j) o[j] = make_float4(0.f, 0.f, 0.f, 0.f);
    float m = -INFINITY, l = 0.f;

    const float4* kp = (const float4*)(Kg + hbase);
    const float4* vp = (const float4*)(Vg + hbase);

    for (int kt = 0; kt < NKT; ++kt) {
        __syncthreads();   // previous tile fully consumed
        // Stage K,V tile: 1024 float4 each, 16 per lane, coalesced.
#pragma unroll
        for (int j = 0; j < D4; ++j) {
            Ks[t + QB * j] = kp[kt * (KB * D4) + t + QB * j];
            Vs[t + QB * j] = vp[kt * (KB * D4) + t + QB * j];
        }
        __syncthreads();
        // k2 for row t of the tile.
        {
            float acc = 0.f;
#pragma unroll
            for (int j = 0; j < D4; ++j) {
                float4 kv = Ks[t * D4 + j];
                acc += kv.x * kv.x + kv.y * kv.y + kv.z * kv.z + kv.w * kv.w;
            }
            k2s[t] = acc;
        }
        __syncthreads();

        // 4 sub-tiles of 16 keys: score pass (tile max) then exp+PV pass.
#pragma unroll
        for (int st = 0; st < KB / 16; ++st) {
            float sc[16];
            float tmax = -INFINITY;
#pragma unroll
            for (int r16 = 0; r16 < 16; ++r16) {
                const int r = st * 16 + r16;
                float ax = 0.f, ay = 0.f, az = 0.f, aw = 0.f;
#pragma unroll
                for (int j = 0; j < D4; ++j) {
                    float4 kv = Ks[r * D4 + j];   // wave-broadcast, no conflicts
                    ax = fmaf(qr[j].x, kv.x, ax);
                    ay = fmaf(qr[j].y, kv.y, ay);
                    az = fmaf(qr[j].z, kv.z, az);
                    aw = fmaf(qr[j].w, kv.w, aw);
                }
                const float dot = (ax + ay) + (az + aw);
                const float k2  = k2s[r];
                const float sq  = fmaxf(fmaf(-2.f, dot, q2 + k2), 0.f);
                const float s   = (k2 - sqrtf(sq)) * (1.f / 16.f);
                sc[r16] = s;
                tmax = fmaxf(tmax, s);
            }
            const float nm    = fmaxf(m, tmax);
            const float scale = __expf(m - nm);   // m=-inf first pass -> 0
            l *= scale;
#pragma unroll
            for (int j = 0; j < D4; ++j) {
                o[j].x *= scale; o[j].y *= scale;
                o[j].z *= scale; o[j].w *= scale;
            }
            m = nm;
#pragma unroll
            for (int r16 = 0; r16 < 16; ++r16) {
                const int r = st * 16 + r16;
                const float p = __expf(sc[r16] - m);
                l += p;
#pragma unroll
                for (int j = 0; j < D4; ++j) {
                    float4 vv = Vs[r * D4 + j];   // wave-broadcast
                    o[j].x = fmaf(p, vv.x, o[j].x);
                    o[j].y = fmaf(p, vv.y, o[j].y);
                    o[j].z = fmaf(p, vv.z, o[j].z);
                    o[j].w = fmaf(p, vv.w, o[j].w);
                }
            }
        }
    }

    const float inv_l = 1.f / l;
    float4* op = (float4*)(Og + hbase + (size_t)q * DIM);
#pragma unroll
    for (int j = 0; j < D4; ++j) {
        op[j] = make_float4(o[j].x * inv_l, o[j].y * inv_l,
                            o[j].z * inv_l, o[j].w * inv_l);
    }
}

extern "C" void kernel_launch(void* const* d_in, const int* in_sizes, int n_in,
                              void* d_out, int out_size, void* d_ws, size_t ws_size,
                              hipStream_t stream) {
    const float* Q = (const float*)d_in[0];
    const float* K = (const float*)d_in[1];
    const float* V = (const float*)d_in[2];
    float* O = (float*)d_out;

    dim3 grid(SEQ / QB, BH);   // 32 x 32 = 1024 blocks
    dim3 block(64);
    se_attn_fp32<<<grid, block, 0, stream>>>(Q, K, V, O);
}

// Round 2
// 161.641 us; speedup vs baseline: 12.6614x; 12.6614x over previous
//
#include <hip/hip_runtime.h>
#include <hip/hip_bf16.h>
#include <math.h>

// SE (RBF) kernel attention via bf16 MFMA flash attention.
// score = (k2 - sqrt(max(q2 - 2 q.k + k2, 0)))/16  (q2 term cancels in softmax)
// Swapped QK^T: ST[k][q] = mfma(A=K, B=Q^T)  -> lane holds q = lane&15
// Swapped PV:   O^T[d][q] = mfma(A=V^T, B=P^T)
// q2/k2 in fp32 (logit-critical); q.k and PV in bf16 MFMA.

typedef __attribute__((ext_vector_type(8))) short bf16x8;
typedef __attribute__((ext_vector_type(4))) float f32x4;

#define SEQ   2048
#define DIM   64
#define NHEAD 32
#define QBLK  64          // queries per block (4 waves x 16)
#define KVB   64          // keys per tile
#define NKT   (SEQ / KVB)

__device__ __forceinline__ unsigned int f2bf(float f) {
    __hip_bfloat16 h = __float2bfloat16(f);   // RNE
    unsigned short u;
    __builtin_memcpy(&u, &h, 2);
    return (unsigned int)u;
}

__global__ __launch_bounds__(256, 4)
void se_attn_mfma(const float* __restrict__ Qg, const float* __restrict__ Kg,
                  const float* __restrict__ Vg, float* __restrict__ Og) {
    __shared__ char  Kl[KVB * 128];      // bf16 K[k][d], row-XOR-swizzled
    __shared__ char  Vt[DIM * 128];      // bf16 V^T[d][k], row-XOR-swizzled
    __shared__ char  Pl[4][16 * 128];    // per-wave bf16 P[q][k], row-XOR-swizzled
    __shared__ float k2s[KVB];

    const int tid = threadIdx.x;
    const int w   = tid >> 6;            // wave 0..3
    const int l   = tid & 63;
    const int lq  = l & 15;              // q index within wave tile / MFMA row
    const int g   = l >> 4;              // lane group
    const size_t hb = (size_t)blockIdx.y * (SEQ * DIM);
    const int q = blockIdx.x * QBLK + w * 16 + lq;
    char* Pw = Pl[w];
    const int swq = (lq & 7) << 4;       // XOR swizzle for rows congruent to lq mod 8

    // ---- Q B-fragments (2 K-halves) + q2 (fp32) ----
    bf16x8 qf[2];
    float q2 = 0.f;
#pragma unroll
    for (int h = 0; h < 2; ++h) {
        const float* qp = Qg + hb + (size_t)q * DIM + h * 32 + g * 8;
        f32x4 a = *(const f32x4*)qp;
        f32x4 b = *(const f32x4*)(qp + 4);
#pragma unroll
        for (int j = 0; j < 4; ++j) {
            q2 += a[j] * a[j] + b[j] * b[j];
            qf[h][j]     = (short)f2bf(a[j]);
            qf[h][4 + j] = (short)f2bf(b[j]);
        }
    }
    q2 += __shfl_xor(q2, 16);
    q2 += __shfl_xor(q2, 32);

    f32x4 ofr[4];
#pragma unroll
    for (int i = 0; i < 4; ++i) ofr[i] = (f32x4){0.f, 0.f, 0.f, 0.f};
    float m = -INFINITY, lsum = 0.f;

    // staging index precompute
    const int srow = tid >> 2;           // K row 0..63
    const int sc4  = tid & 3;            // which 16-d chunk
    const int vpr  = tid & 31;           // V k-pair (keys 2*vpr, 2*vpr+1)
    const int vd0  = (tid >> 5) * 8;     // V d-base (8 d's)

    for (int kt = 0; kt < NKT; ++kt) {
        __syncthreads();                 // previous tile fully consumed
        // ---- stage K (bf16, swizzled) + k2 (fp32) ----
        {
            const float* kp = Kg + hb + (size_t)(kt * KVB + srow) * DIM + sc4 * 16;
            f32x4 a = *(const f32x4*)kp;
            f32x4 b = *(const f32x4*)(kp + 4);
            f32x4 c = *(const f32x4*)(kp + 8);
            f32x4 d = *(const f32x4*)(kp + 12);
            float part = 0.f;
#pragma unroll
            for (int j = 0; j < 4; ++j)
                part += a[j]*a[j] + b[j]*b[j] + c[j]*c[j] + d[j]*d[j];
            part += __shfl_xor(part, 1);
            part += __shfl_xor(part, 2);
            if (sc4 == 0) k2s[srow] = part;
            bf16x8 p0, p1;
#pragma unroll
            for (int j = 0; j < 4; ++j) {
                p0[j]     = (short)f2bf(a[j]);
                p0[4 + j] = (short)f2bf(b[j]);
                p1[j]     = (short)f2bf(c[j]);
                p1[4 + j] = (short)f2bf(d[j]);
            }
            const int sw = (srow & 7) << 4;
            const int wa = srow * 128 + sc4 * 32;
            *(bf16x8*)(Kl + (wa ^ sw))        = p0;
            *(bf16x8*)(Kl + ((wa + 16) ^ sw)) = p1;
        }
        // ---- stage V^T (bf16 pairs along k, swizzled) ----
        {
            const float* vp = Vg + hb + (size_t)(kt * KVB + 2 * vpr) * DIM + vd0;
            f32x4 a0 = *(const f32x4*)vp;
            f32x4 a1 = *(const f32x4*)(vp + 4);
            f32x4 b0 = *(const f32x4*)(vp + DIM);
            f32x4 b1 = *(const f32x4*)(vp + DIM + 4);
#pragma unroll
            for (int j = 0; j < 8; ++j) {
                const float lo = (j < 4) ? a0[j] : a1[j - 4];
                const float hi = (j < 4) ? b0[j] : b1[j - 4];
                const unsigned int pk = f2bf(lo) | (f2bf(hi) << 16);
                const int d = vd0 + j;
                const int wa = d * 128 + vpr * 4;
                *(unsigned int*)(Vt + (wa ^ ((d & 7) << 4))) = pk;
            }
        }
        __syncthreads();

        // ---- QK^T (swapped): ST[k][q], 4 k-frags x 2 K-halves ----
        f32x4 st[4];
#pragma unroll
        for (int f = 0; f < 4; ++f) st[f] = (f32x4){0.f, 0.f, 0.f, 0.f};
#pragma unroll
        for (int f = 0; f < 4; ++f) {
#pragma unroll
            for (int h = 0; h < 2; ++h) {
                const int ra = (f * 16 + lq) * 128 + h * 64 + g * 16;
                bf16x8 kf = *(const bf16x8*)(Kl + (ra ^ swq));
                st[f] = __builtin_amdgcn_mfma_f32_16x16x32_bf16(kf, qf[h], st[f], 0, 0, 0);
            }
        }

        // ---- scores + online softmax (lane holds k = 16f+4g+r for its q) ----
        float sc[4][4];
        float tmax = -INFINITY;
#pragma unroll
        for (int f = 0; f < 4; ++f) {
            const f32x4 k2v = *(const f32x4*)(k2s + f * 16 + g * 4);
#pragma unroll
            for (int r = 0; r < 4; ++r) {
                const float kk = k2v[r];
                const float sq = fmaxf(fmaf(-2.f, st[f][r], q2 + kk), 0.f);
                const float s  = (kk - sqrtf(sq)) * 0.0625f;
                sc[f][r] = s;
                tmax = fmaxf(tmax, s);
            }
        }
        tmax = fmaxf(tmax, __shfl_xor(tmax, 16));
        tmax = fmaxf(tmax, __shfl_xor(tmax, 32));
        const float nm    = fmaxf(m, tmax);
        const float scale = __expf(m - nm);   // 0 on first tile
        m = nm;
        lsum *= scale;
#pragma unroll
        for (int i = 0; i < 4; ++i) {
            ofr[i][0] *= scale; ofr[i][1] *= scale;
            ofr[i][2] *= scale; ofr[i][3] *= scale;
        }
        // p = exp(s-m), pack pairs along k, write to per-wave P_lds[q][k]
#pragma unroll
        for (int f = 0; f < 4; ++f) {
#pragma unroll
            for (int e = 0; e < 2; ++e) {
                const float p0 = __expf(sc[f][2 * e]     - m);
                const float p1 = __expf(sc[f][2 * e + 1] - m);
                lsum += p0 + p1;
                const unsigned int pk = f2bf(p0) | (f2bf(p1) << 16);
                const int pr = 8 * f + 2 * g + e;        // k-pair index
                const int wa = lq * 128 + pr * 4;
                *(unsigned int*)(Pw + (wa ^ swq)) = pk;
            }
        }

        // ---- PV (swapped): O^T[d][q] += V^T . P^T ----
        bf16x8 pf[2];
#pragma unroll
        for (int h = 0; h < 2; ++h) {
            const int ra = lq * 128 + h * 64 + g * 16;
            pf[h] = *(const bf16x8*)(Pw + (ra ^ swq));
        }
#pragma unroll
        for (int db = 0; db < 4; ++db) {
#pragma unroll
            for (int h = 0; h < 2; ++h) {
                const int ra = (db * 16 + lq) * 128 + h * 64 + g * 16;
                bf16x8 vf = *(const bf16x8*)(Vt + (ra ^ swq));
                ofr[db] = __builtin_amdgcn_mfma_f32_16x16x32_bf16(vf, pf[h], ofr[db], 0, 0, 0);
            }
        }
    }

    // ---- finalize: combine l partials across lane groups, normalize, store ----
    lsum += __shfl_xor(lsum, 16);
    lsum += __shfl_xor(lsum, 32);
    const float inv = 1.f / lsum;
    float* op = Og + hb + (size_t)q * DIM;
#pragma unroll
    for (int db = 0; db < 4; ++db) {
#pragma unroll
        for (int r = 0; r < 4; ++r) {
            op[db * 16 + g * 4 + r] = ofr[db][r] * inv;   // d = 16*db + 4*g + r
        }
    }
}

extern "C" void kernel_launch(void* const* d_in, const int* in_sizes, int n_in,
                              void* d_out, int out_size, void* d_ws, size_t ws_size,
                              hipStream_t stream) {
    const float* Q = (const float*)d_in[0];
    const float* K = (const float*)d_in[1];
    const float* V = (const float*)d_in[2];
    float* O = (float*)d_out;

    dim3 grid(SEQ / QBLK, NHEAD);   // 32 x 32
    dim3 block(256);
    se_attn_mfma<<<grid, block, 0, stream>>>(Q, K, V, O);
}

// Round 3
// 138.777 us; speedup vs baseline: 14.7474x; 1.1648x over previous
//
#include <hip/hip_runtime.h>
#include <hip/hip_bf16.h>
#include <math.h>

// SE (RBF) kernel attention via bf16 MFMA flash attention, prepacked K/V.
// score = (k2 - sqrt(max(q2 - 2 q.k + k2, 0)))/16  (q2 term cancels in softmax)
// Prep kernel: K -> bf16 swizzled tile images, V -> bf16 V^T swizzled tile
// images, k2 fp32. Main kernel: global_load_lds(16B) double-buffered staging,
// swapped-operand MFMA (ST[k][q] = mfma(K, Q^T); O^T = mfma(V^T, P^T)),
// online softmax with defer-max.

typedef __attribute__((ext_vector_type(8))) short bf16x8;
typedef __attribute__((ext_vector_type(4))) float f32x4;

#define SEQ    2048
#define DIM    64
#define NHEAD  32
#define QBLK   64          // queries per block (4 waves x 16)
#define KVB    64          // keys per tile
#define NKT    (SEQ / KVB)
#define TILE_B 8192        // bytes per bf16 64x64 tile image

__device__ __forceinline__ unsigned int f2bf(float f) {
    __hip_bfloat16 h = __float2bfloat16(f);   // RNE
    unsigned short u;
    __builtin_memcpy(&u, &h, 2);
    return (unsigned int)u;
}

__device__ __forceinline__ void gl_lds16(const void* g, void* l) {
    __builtin_amdgcn_global_load_lds(
        (const __attribute__((address_space(1))) unsigned int*)g,
        (__attribute__((address_space(3))) unsigned int*)l, 16, 0, 0);
}

// ---------------- prepack: K/V -> bf16 swizzled tile images + k2 -------------
__global__ __launch_bounds__(256, 4)
void prep_kv(const float* __restrict__ Kg, const float* __restrict__ Vg,
             char* __restrict__ Kp, char* __restrict__ Vp,
             float* __restrict__ k2g) {
    __shared__ char Kimg[TILE_B];
    __shared__ char Vimg[TILE_B];

    const int tid  = threadIdx.x;
    const int kt   = blockIdx.x;     // tile 0..31
    const int head = blockIdx.y;     // 0..31
    const size_t hb = (size_t)head * (SEQ * DIM);

    // ---- K tile: bf16 + swizzle + k2 ----
    {
        const int row = tid >> 2;    // 0..63
        const int sc4 = tid & 3;     // 16-d chunk
        const float* kp = Kg + hb + (size_t)(kt * KVB + row) * DIM + sc4 * 16;
        f32x4 a = *(const f32x4*)kp;
        f32x4 b = *(const f32x4*)(kp + 4);
        f32x4 c = *(const f32x4*)(kp + 8);
        f32x4 d = *(const f32x4*)(kp + 12);
        float part = 0.f;
#pragma unroll
        for (int j = 0; j < 4; ++j)
            part += a[j]*a[j] + b[j]*b[j] + c[j]*c[j] + d[j]*d[j];
        part += __shfl_xor(part, 1);
        part += __shfl_xor(part, 2);
        if (sc4 == 0) k2g[head * SEQ + kt * KVB + row] = part;
        bf16x8 p0, p1;
#pragma unroll
        for (int j = 0; j < 4; ++j) {
            p0[j]     = (short)f2bf(a[j]);
            p0[4 + j] = (short)f2bf(b[j]);
            p1[j]     = (short)f2bf(c[j]);
            p1[4 + j] = (short)f2bf(d[j]);
        }
        const int sw = (row & 7) << 4;
        const int wa = row * 128 + sc4 * 32;
        *(bf16x8*)(Kimg + (wa ^ sw))        = p0;
        *(bf16x8*)(Kimg + ((wa + 16) ^ sw)) = p1;
    }
    // ---- V^T tile: bf16 pairs along k + swizzle ----
    {
        const int vpr = tid & 31;          // key pair (2*vpr, 2*vpr+1)
        const int vd0 = (tid >> 5) * 8;    // 8 d's
        const float* vp = Vg + hb + (size_t)(kt * KVB + 2 * vpr) * DIM + vd0;
        f32x4 a0 = *(const f32x4*)vp;
        f32x4 a1 = *(const f32x4*)(vp + 4);
        f32x4 b0 = *(const f32x4*)(vp + DIM);
        f32x4 b1 = *(const f32x4*)(vp + DIM + 4);
#pragma unroll
        for (int j = 0; j < 8; ++j) {
            const float lo = (j < 4) ? a0[j] : a1[j - 4];
            const float hi = (j < 4) ? b0[j] : b1[j - 4];
            const unsigned int pk = f2bf(lo) | (f2bf(hi) << 16);
            const int d  = vd0 + j;
            const int wa = d * 128 + vpr * 4;
            *(unsigned int*)(Vimg + (wa ^ ((d & 7) << 4))) = pk;
        }
    }
    __syncthreads();
    // ---- copy images to global, linear/coalesced ----
    char* kdst = Kp + (size_t)(head * NKT + kt) * TILE_B;
    char* vdst = Vp + (size_t)(head * NKT + kt) * TILE_B;
#pragma unroll
    for (int s = 0; s < 2; ++s) {
        *(f32x4*)(kdst + s * 4096 + tid * 16) = *(const f32x4*)(Kimg + s * 4096 + tid * 16);
        *(f32x4*)(vdst + s * 4096 + tid * 16) = *(const f32x4*)(Vimg + s * 4096 + tid * 16);
    }
}

// ---------------- main: flash attention over prepacked tiles -----------------
__global__ __launch_bounds__(256, 4)
void se_attn_main(const float* __restrict__ Qg, const char* __restrict__ Kp,
                  const char* __restrict__ Vp, const float* __restrict__ k2g,
                  float* __restrict__ Og) {
    __shared__ char Kbuf[2][TILE_B];
    __shared__ char Vbuf[2][TILE_B];
    __shared__ char Pl[4][2048];

    const int tid = threadIdx.x;
    const int w   = tid >> 6;
    const int l   = tid & 63;
    const int lq  = l & 15;
    const int g   = l >> 4;
    const int head = blockIdx.y;
    const size_t hb = (size_t)head * (SEQ * DIM);
    const int q = blockIdx.x * QBLK + w * 16 + lq;
    char* Pw = Pl[w];
    const int swq = (lq & 7) << 4;

    const char*  Kph = Kp + (size_t)head * NKT * TILE_B;
    const char*  Vph = Vp + (size_t)head * NKT * TILE_B;
    const float* k2h = k2g + head * SEQ;

    // ---- Q B-fragments + q2 (fp32) ----
    bf16x8 qf[2];
    float q2 = 0.f;
#pragma unroll
    for (int h = 0; h < 2; ++h) {
        const float* qp = Qg + hb + (size_t)q * DIM + h * 32 + g * 8;
        f32x4 a = *(const f32x4*)qp;
        f32x4 b = *(const f32x4*)(qp + 4);
#pragma unroll
        for (int j = 0; j < 4; ++j) {
            q2 += a[j] * a[j] + b[j] * b[j];
            qf[h][j]     = (short)f2bf(a[j]);
            qf[h][4 + j] = (short)f2bf(b[j]);
        }
    }
    q2 += __shfl_xor(q2, 16);
    q2 += __shfl_xor(q2, 32);

    f32x4 ofr[4];
#pragma unroll
    for (int i = 0; i < 4; ++i) ofr[i] = (f32x4){0.f, 0.f, 0.f, 0.f};
    float m = -INFINITY, lsum = 0.f;

    const int soff = w * 1024 + l * 16;   // per-lane stage offset

    // prologue: stage tile 0 -> buf 0
#pragma unroll
    for (int s = 0; s < 2; ++s) {
        gl_lds16(Kph + s * 4096 + soff, Kbuf[0] + s * 4096 + w * 1024);
        gl_lds16(Vph + s * 4096 + soff, Vbuf[0] + s * 4096 + w * 1024);
    }
    __syncthreads();

    int cur = 0;
    for (int kt = 0; kt < NKT; ++kt) {
        // k2 for this tile (issued BEFORE stage loads so the compiler's wait
        // for k2 is vmcnt(4), leaving the prefetch in flight)
        f32x4 k2v[4];
#pragma unroll
        for (int f = 0; f < 4; ++f)
            k2v[f] = *(const f32x4*)(k2h + kt * KVB + f * 16 + g * 4);

        // prefetch next tile into the other buffer
        if (kt + 1 < NKT) {
            const char* ktp = Kph + (size_t)(kt + 1) * TILE_B;
            const char* vtp = Vph + (size_t)(kt + 1) * TILE_B;
            char* kd = Kbuf[cur ^ 1];
            char* vd = Vbuf[cur ^ 1];
#pragma unroll
            for (int s = 0; s < 2; ++s) {
                gl_lds16(ktp + s * 4096 + soff, kd + s * 4096 + w * 1024);
                gl_lds16(vtp + s * 4096 + soff, vd + s * 4096 + w * 1024);
            }
        }

        const char* Kl = Kbuf[cur];
        const char* Vt = Vbuf[cur];

        // ---- QK^T (swapped): ST[k][q] ----
        f32x4 st[4];
#pragma unroll
        for (int f = 0; f < 4; ++f) st[f] = (f32x4){0.f, 0.f, 0.f, 0.f};
#pragma unroll
        for (int f = 0; f < 4; ++f) {
#pragma unroll
            for (int h = 0; h < 2; ++h) {
                const int ra = (f * 16 + lq) * 128 + h * 64 + g * 16;
                bf16x8 kf = *(const bf16x8*)(Kl + (ra ^ swq));
                st[f] = __builtin_amdgcn_mfma_f32_16x16x32_bf16(kf, qf[h], st[f], 0, 0, 0);
            }
        }

        // ---- scores + online softmax ----
        float sc[4][4];
        float tmax = -INFINITY;
#pragma unroll
        for (int f = 0; f < 4; ++f) {
#pragma unroll
            for (int r = 0; r < 4; ++r) {
                const float kk = k2v[f][r];
                const float sq = fmaxf(fmaf(-2.f, st[f][r], q2 + kk), 0.f);
                const float s  = (kk - sqrtf(sq)) * 0.0625f;
                sc[f][r] = s;
                tmax = fmaxf(tmax, s);
            }
        }
        tmax = fmaxf(tmax, __shfl_xor(tmax, 16));
        tmax = fmaxf(tmax, __shfl_xor(tmax, 32));
        // defer-max (T13): only rescale when the max actually grows (THR=8)
        if (tmax > m + 8.f) {
            const float scale = __expf(m - tmax);   // 0 on first tile
            m = tmax;
            lsum *= scale;
#pragma unroll
            for (int i = 0; i < 4; ++i) {
                ofr[i][0] *= scale; ofr[i][1] *= scale;
                ofr[i][2] *= scale; ofr[i][3] *= scale;
            }
        }
        // p = exp(s-m) (bounded by e^8), pack pairs, write per-wave P_lds
#pragma unroll
        for (int f = 0; f < 4; ++f) {
#pragma unroll
            for (int e = 0; e < 2; ++e) {
                const float p0 = __expf(sc[f][2 * e]     - m);
                const float p1 = __expf(sc[f][2 * e + 1] - m);
                lsum += p0 + p1;
                const unsigned int pk = f2bf(p0) | (f2bf(p1) << 16);
                const int pr = 8 * f + 2 * g + e;
                const int wa = lq * 128 + pr * 4;
                *(unsigned int*)(Pw + (wa ^ swq)) = pk;
            }
        }

        // ---- PV (swapped): O^T[d][q] += V^T . P^T ----
        bf16x8 pf[2];
#pragma unroll
        for (int h = 0; h < 2; ++h) {
            const int ra = lq * 128 + h * 64 + g * 16;
            pf[h] = *(const bf16x8*)(Pw + (ra ^ swq));
        }
#pragma unroll
        for (int db = 0; db < 4; ++db) {
#pragma unroll
            for (int h = 0; h < 2; ++h) {
                const int ra = (db * 16 + lq) * 128 + h * 64 + g * 16;
                bf16x8 vf = *(const bf16x8*)(Vt + (ra ^ swq));
                ofr[db] = __builtin_amdgcn_mfma_f32_16x16x32_bf16(vf, pf[h], ofr[db], 0, 0, 0);
            }
        }

        __syncthreads();   // drains stage loads (vmcnt 0) + all reads of buf[cur]
        cur ^= 1;
    }

    // ---- finalize ----
    lsum += __shfl_xor(lsum, 16);
    lsum += __shfl_xor(lsum, 32);
    const float inv = 1.f / lsum;
    float* op = Og + hb + (size_t)q * DIM;
#pragma unroll
    for (int db = 0; db < 4; ++db) {
#pragma unroll
        for (int r = 0; r < 4; ++r) {
            op[db * 16 + g * 4 + r] = ofr[db][r] * inv;
        }
    }
}

// ---------------- fallback (no-workspace monolithic, round-2 kernel) ---------
__global__ __launch_bounds__(256, 4)
void se_attn_mfma(const float* __restrict__ Qg, const float* __restrict__ Kg,
                  const float* __restrict__ Vg, float* __restrict__ Og) {
    __shared__ char  Kl[KVB * 128];
    __shared__ char  Vt[DIM * 128];
    __shared__ char  Pl[4][16 * 128];
    __shared__ float k2s[KVB];

    const int tid = threadIdx.x;
    const int w   = tid >> 6;
    const int l   = tid & 63;
    const int lq  = l & 15;
    const int g   = l >> 4;
    const size_t hb = (size_t)blockIdx.y * (SEQ * DIM);
    const int q = blockIdx.x * QBLK + w * 16 + lq;
    char* Pw = Pl[w];
    const int swq = (lq & 7) << 4;

    bf16x8 qf[2];
    float q2 = 0.f;
#pragma unroll
    for (int h = 0; h < 2; ++h) {
        const float* qp = Qg + hb + (size_t)q * DIM + h * 32 + g * 8;
        f32x4 a = *(const f32x4*)qp;
        f32x4 b = *(const f32x4*)(qp + 4);
#pragma unroll
        for (int j = 0; j < 4; ++j) {
            q2 += a[j] * a[j] + b[j] * b[j];
            qf[h][j]     = (short)f2bf(a[j]);
            qf[h][4 + j] = (short)f2bf(b[j]);
        }
    }
    q2 += __shfl_xor(q2, 16);
    q2 += __shfl_xor(q2, 32);

    f32x4 ofr[4];
#pragma unroll
    for (int i = 0; i < 4; ++i) ofr[i] = (f32x4){0.f, 0.f, 0.f, 0.f};
    float m = -INFINITY, lsum = 0.f;

    const int srow = tid >> 2;
    const int sc4  = tid & 3;
    const int vpr  = tid & 31;
    const int vd0  = (tid >> 5) * 8;

    for (int kt = 0; kt < NKT; ++kt) {
        __syncthreads();
        {
            const float* kp = Kg + hb + (size_t)(kt * KVB + srow) * DIM + sc4 * 16;
            f32x4 a = *(const f32x4*)kp;
            f32x4 b = *(const f32x4*)(kp + 4);
            f32x4 c = *(const f32x4*)(kp + 8);
            f32x4 d = *(const f32x4*)(kp + 12);
            float part = 0.f;
#pragma unroll
            for (int j = 0; j < 4; ++j)
                part += a[j]*a[j] + b[j]*b[j] + c[j]*c[j] + d[j]*d[j];
            part += __shfl_xor(part, 1);
            part += __shfl_xor(part, 2);
            if (sc4 == 0) k2s[srow] = part;
            bf16x8 p0, p1;
#pragma unroll
            for (int j = 0; j < 4; ++j) {
                p0[j]     = (short)f2bf(a[j]);
                p0[4 + j] = (short)f2bf(b[j]);
                p1[j]     = (short)f2bf(c[j]);
                p1[4 + j] = (short)f2bf(d[j]);
            }
            const int sw = (srow & 7) << 4;
            const int wa = srow * 128 + sc4 * 32;
            *(bf16x8*)(Kl + (wa ^ sw))        = p0;
            *(bf16x8*)(Kl + ((wa + 16) ^ sw)) = p1;
        }
        {
            const float* vp = Vg + hb + (size_t)(kt * KVB + 2 * vpr) * DIM + vd0;
            f32x4 a0 = *(const f32x4*)vp;
            f32x4 a1 = *(const f32x4*)(vp + 4);
            f32x4 b0 = *(const f32x4*)(vp + DIM);
            f32x4 b1 = *(const f32x4*)(vp + DIM + 4);
#pragma unroll
            for (int j = 0; j < 8; ++j) {
                const float lo = (j < 4) ? a0[j] : a1[j - 4];
                const float hi = (j < 4) ? b0[j] : b1[j - 4];
                const unsigned int pk = f2bf(lo) | (f2bf(hi) << 16);
                const int d = vd0 + j;
                const int wa = d * 128 + vpr * 4;
                *(unsigned int*)(Vt + (wa ^ ((d & 7) << 4))) = pk;
            }
        }
        __syncthreads();

        f32x4 st[4];
#pragma unroll
        for (int f = 0; f < 4; ++f) st[f] = (f32x4){0.f, 0.f, 0.f, 0.f};
#pragma unroll
        for (int f = 0; f < 4; ++f) {
#pragma unroll
            for (int h = 0; h < 2; ++h) {
                const int ra = (f * 16 + lq) * 128 + h * 64 + g * 16;
                bf16x8 kf = *(const bf16x8*)(Kl + (ra ^ swq));
                st[f] = __builtin_amdgcn_mfma_f32_16x16x32_bf16(kf, qf[h], st[f], 0, 0, 0);
            }
        }

        float sc[4][4];
        float tmax = -INFINITY;
#pragma unroll
        for (int f = 0; f < 4; ++f) {
            const f32x4 k2v = *(const f32x4*)(k2s + f * 16 + g * 4);
#pragma unroll
            for (int r = 0; r < 4; ++r) {
                const float kk = k2v[r];
                const float sq = fmaxf(fmaf(-2.f, st[f][r], q2 + kk), 0.f);
                const float s  = (kk - sqrtf(sq)) * 0.0625f;
                sc[f][r] = s;
                tmax = fmaxf(tmax, s);
            }
        }
        tmax = fmaxf(tmax, __shfl_xor(tmax, 16));
        tmax = fmaxf(tmax, __shfl_xor(tmax, 32));
        const float nm    = fmaxf(m, tmax);
        const float scale = __expf(m - nm);
        m = nm;
        lsum *= scale;
#pragma unroll
        for (int i = 0; i < 4; ++i) {
            ofr[i][0] *= scale; ofr[i][1] *= scale;
            ofr[i][2] *= scale; ofr[i][3] *= scale;
        }
#pragma unroll
        for (int f = 0; f < 4; ++f) {
#pragma unroll
            for (int e = 0; e < 2; ++e) {
                const float p0 = __expf(sc[f][2 * e]     - m);
                const float p1 = __expf(sc[f][2 * e + 1] - m);
                lsum += p0 + p1;
                const unsigned int pk = f2bf(p0) | (f2bf(p1) << 16);
                const int pr = 8 * f + 2 * g + e;
                const int wa = lq * 128 + pr * 4;
                *(unsigned int*)(Pw + (wa ^ swq)) = pk;
            }
        }

        bf16x8 pf[2];
#pragma unroll
        for (int h = 0; h < 2; ++h) {
            const int ra = lq * 128 + h * 64 + g * 16;
            pf[h] = *(const bf16x8*)(Pw + (ra ^ swq));
        }
#pragma unroll
        for (int db = 0; db < 4; ++db) {
#pragma unroll
            for (int h = 0; h < 2; ++h) {
                const int ra = (db * 16 + lq) * 128 + h * 64 + g * 16;
                bf16x8 vf = *(const bf16x8*)(Vt + (ra ^ swq));
                ofr[db] = __builtin_amdgcn_mfma_f32_16x16x32_bf16(vf, pf[h], ofr[db], 0, 0, 0);
            }
        }
    }

    lsum += __shfl_xor(lsum, 16);
    lsum += __shfl_xor(lsum, 32);
    const float inv = 1.f / lsum;
    float* op = Og + hb + (size_t)q * DIM;
#pragma unroll
    for (int db = 0; db < 4; ++db) {
#pragma unroll
        for (int r = 0; r < 4; ++r) {
            op[db * 16 + g * 4 + r] = ofr[db][r] * inv;
        }
    }
}

extern "C" void kernel_launch(void* const* d_in, const int* in_sizes, int n_in,
                              void* d_out, int out_size, void* d_ws, size_t ws_size,
                              hipStream_t stream) {
    const float* Q = (const float*)d_in[0];
    const float* K = (const float*)d_in[1];
    const float* V = (const float*)d_in[2];
    float* O = (float*)d_out;

    const size_t KP_B = (size_t)NHEAD * NKT * TILE_B;   // 8 MB
    const size_t need = 2 * KP_B + (size_t)NHEAD * SEQ * 4;

    if (ws_size >= need) {
        char*  Kp = (char*)d_ws;
        char*  Vp = Kp + KP_B;
        float* k2 = (float*)(Kp + 2 * KP_B);
        prep_kv<<<dim3(NKT, NHEAD), 256, 0, stream>>>(K, V, Kp, Vp, k2);
        se_attn_main<<<dim3(SEQ / QBLK, NHEAD), 256, 0, stream>>>(Q, Kp, Vp, k2, O);
    } else {
        se_attn_mfma<<<dim3(SEQ / QBLK, NHEAD), 256, 0, stream>>>(Q, K, V, O);
    }
}

// Round 5
// 97.926 us; speedup vs baseline: 20.8994x; 1.4172x over previous
//
#include <hip/hip_runtime.h>
#include <hip/hip_bf16.h>
#include <math.h>

// SE (RBF) kernel attention via bf16 MFMA flash attention, prepacked K/V.
// score = (k2 - sqrt(max(q2 - 2 q.k + k2, 0)))/16  (q2 term cancels in softmax)
// All softmax math in log2-units: s~ = C*(k2 - dist), C = log2(e)/16, so
// p = exp2(s~ - m~) == exp(s - m) exactly. k2*C prepacked (k2c).
// Main kernel: 8 waves/block (128 q), global_load_lds(16B) double-buffered
// staging, swapped-operand MFMA, online softmax with defer-max.

typedef __attribute__((ext_vector_type(8))) short bf16x8;
typedef __attribute__((ext_vector_type(4))) float f32x4;

#define SEQ    2048
#define DIM    64
#define NHEAD  32
#define QBLK   128         // queries per block (8 waves x 16)
#define KVB    64          // keys per tile
#define NKT    (SEQ / KVB)
#define TILE_B 8192        // bytes per bf16 64x64 tile image
#define C2     0.0901684403f    // log2(e)/16
#define THR2   11.5415603f      // 8 * log2(e)

__device__ __forceinline__ float fast_exp2(float x) { return __builtin_amdgcn_exp2f(x); }
__device__ __forceinline__ float fast_sqrt(float x) { return __builtin_amdgcn_sqrtf(x); }

__device__ __forceinline__ unsigned int f2bf(float f) {
    __hip_bfloat16 h = __float2bfloat16(f);   // RNE
    unsigned short u;
    __builtin_memcpy(&u, &h, 2);
    return (unsigned int)u;
}

__device__ __forceinline__ void gl_lds16(const void* g, void* l) {
    __builtin_amdgcn_global_load_lds(
        (const __attribute__((address_space(1))) unsigned int*)g,
        (__attribute__((address_space(3))) unsigned int*)l, 16, 0, 0);
}

// ---------------- prepack: K/V -> bf16 swizzled tile images + k2, k2c --------
__global__ __launch_bounds__(256, 4)
void prep_kv(const float* __restrict__ Kg, const float* __restrict__ Vg,
             char* __restrict__ Kp, char* __restrict__ Vp,
             float* __restrict__ k2g, float* __restrict__ k2cg) {
    __shared__ char Kimg[TILE_B];
    __shared__ char Vimg[TILE_B];

    const int tid  = threadIdx.x;
    const int kt   = blockIdx.x;     // tile 0..31
    const int head = blockIdx.y;     // 0..31
    const size_t hb = (size_t)head * (SEQ * DIM);

    // ---- K tile: bf16 + swizzle + k2/k2c ----
    {
        const int row = tid >> 2;    // 0..63
        const int sc4 = tid & 3;     // 16-d chunk
        const float* kp = Kg + hb + (size_t)(kt * KVB + row) * DIM + sc4 * 16;
        f32x4 a = *(const f32x4*)kp;
        f32x4 b = *(const f32x4*)(kp + 4);
        f32x4 c = *(const f32x4*)(kp + 8);
        f32x4 d = *(const f32x4*)(kp + 12);
        float part = 0.f;
#pragma unroll
        for (int j = 0; j < 4; ++j)
            part += a[j]*a[j] + b[j]*b[j] + c[j]*c[j] + d[j]*d[j];
        part += __shfl_xor(part, 1);
        part += __shfl_xor(part, 2);
        if (sc4 == 0) {
            k2g[head * SEQ + kt * KVB + row]  = part;
            k2cg[head * SEQ + kt * KVB + row] = part * C2;
        }
        bf16x8 p0, p1;
#pragma unroll
        for (int j = 0; j < 4; ++j) {
            p0[j]     = (short)f2bf(a[j]);
            p0[4 + j] = (short)f2bf(b[j]);
            p1[j]     = (short)f2bf(c[j]);
            p1[4 + j] = (short)f2bf(d[j]);
        }
        const int sw = (row & 7) << 4;
        const int wa = row * 128 + sc4 * 32;
        *(bf16x8*)(Kimg + (wa ^ sw))        = p0;
        *(bf16x8*)(Kimg + ((wa + 16) ^ sw)) = p1;
    }
    // ---- V^T tile: bf16 pairs along k + swizzle ----
    {
        const int vpr = tid & 31;          // key pair (2*vpr, 2*vpr+1)
        const int vd0 = (tid >> 5) * 8;    // 8 d's
        const float* vp = Vg + hb + (size_t)(kt * KVB + 2 * vpr) * DIM + vd0;
        f32x4 a0 = *(const f32x4*)vp;
        f32x4 a1 = *(const f32x4*)(vp + 4);
        f32x4 b0 = *(const f32x4*)(vp + DIM);
        f32x4 b1 = *(const f32x4*)(vp + DIM + 4);
#pragma unroll
        for (int j = 0; j < 8; ++j) {
            const float lo = (j < 4) ? a0[j] : a1[j - 4];
            const float hi = (j < 4) ? b0[j] : b1[j - 4];
            const unsigned int pk = f2bf(lo) | (f2bf(hi) << 16);
            const int d  = vd0 + j;
            const int wa = d * 128 + vpr * 4;
            *(unsigned int*)(Vimg + (wa ^ ((d & 7) << 4))) = pk;
        }
    }
    __syncthreads();
    // ---- copy images to global, linear/coalesced ----
    char* kdst = Kp + (size_t)(head * NKT + kt) * TILE_B;
    char* vdst = Vp + (size_t)(head * NKT + kt) * TILE_B;
#pragma unroll
    for (int s = 0; s < 2; ++s) {
        *(f32x4*)(kdst + s * 4096 + tid * 16) = *(const f32x4*)(Kimg + s * 4096 + tid * 16);
        *(f32x4*)(vdst + s * 4096 + tid * 16) = *(const f32x4*)(Vimg + s * 4096 + tid * 16);
    }
}

// ---------------- main: flash attention over prepacked tiles -----------------
__global__ __launch_bounds__(512, 4)
void se_attn_main(const float* __restrict__ Qg, const char* __restrict__ Kp,
                  const char* __restrict__ Vp, const float* __restrict__ k2g,
                  const float* __restrict__ k2cg, float* __restrict__ Og) {
    __shared__ char Kbuf[2][TILE_B];
    __shared__ char Vbuf[2][TILE_B];
    __shared__ char Pl[8][2048];

    const int tid = threadIdx.x;
    const int w   = tid >> 6;            // wave 0..7
    const int l   = tid & 63;
    const int lq  = l & 15;
    const int g   = l >> 4;
    const int head = blockIdx.y;
    const size_t hb = (size_t)head * (SEQ * DIM);
    const int q = blockIdx.x * QBLK + w * 16 + lq;
    char* Pw = Pl[w];
    const int swq = (lq & 7) << 4;

    const char*  Kph  = Kp + (size_t)head * NKT * TILE_B;
    const char*  Vph  = Vp + (size_t)head * NKT * TILE_B;
    const float* k2h  = k2g  + head * SEQ;
    const float* k2ch = k2cg + head * SEQ;

    // ---- Q B-fragments + q2 (fp32) ----
    bf16x8 qf[2];
    float q2 = 0.f;
#pragma unroll
    for (int h = 0; h < 2; ++h) {
        const float* qp = Qg + hb + (size_t)q * DIM + h * 32 + g * 8;
        f32x4 a = *(const f32x4*)qp;
        f32x4 b = *(const f32x4*)(qp + 4);
#pragma unroll
        for (int j = 0; j < 4; ++j) {
            q2 += a[j] * a[j] + b[j] * b[j];
            qf[h][j]     = (short)f2bf(a[j]);
            qf[h][4 + j] = (short)f2bf(b[j]);
        }
    }
    q2 += __shfl_xor(q2, 16);
    q2 += __shfl_xor(q2, 32);

    f32x4 ofr[4];
#pragma unroll
    for (int i = 0; i < 4; ++i) ofr[i] = (f32x4){0.f, 0.f, 0.f, 0.f};
    float m = -INFINITY, lsA = 0.f, lsB = 0.f;

    // prologue: stage tile 0 -> buf 0 (one 16B chunk per thread per buffer)
    gl_lds16(Kph + tid * 16, Kbuf[0] + w * 1024);
    gl_lds16(Vph + tid * 16, Vbuf[0] + w * 1024);
    __syncthreads();

    int cur = 0;
    for (int kt = 0; kt < NKT; ++kt) {
        // k2 / k2c for this tile (issued before prefetch so their wait
        // leaves the stage loads in flight)
        f32x4 k2v[4], kcv[4];
#pragma unroll
        for (int f = 0; f < 4; ++f) {
            k2v[f] = *(const f32x4*)(k2h  + kt * KVB + f * 16 + g * 4);
            kcv[f] = *(const f32x4*)(k2ch + kt * KVB + f * 16 + g * 4);
        }

        // prefetch next tile into the other buffer
        if (kt + 1 < NKT) {
            const char* ktp = Kph + (size_t)(kt + 1) * TILE_B;
            const char* vtp = Vph + (size_t)(kt + 1) * TILE_B;
            gl_lds16(ktp + tid * 16, Kbuf[cur ^ 1] + w * 1024);
            gl_lds16(vtp + tid * 16, Vbuf[cur ^ 1] + w * 1024);
        }

        const char* Kl = Kbuf[cur];
        const char* Vt = Vbuf[cur];

        // ---- QK^T (swapped): ST[k][q] ----
        f32x4 st[4];
#pragma unroll
        for (int f = 0; f < 4; ++f) st[f] = (f32x4){0.f, 0.f, 0.f, 0.f};
        __builtin_amdgcn_s_setprio(1);
#pragma unroll
        for (int f = 0; f < 4; ++f) {
#pragma unroll
            for (int h = 0; h < 2; ++h) {
                const int ra = (f * 16 + lq) * 128 + h * 64 + g * 16;
                bf16x8 kf = *(const bf16x8*)(Kl + (ra ^ swq));
                st[f] = __builtin_amdgcn_mfma_f32_16x16x32_bf16(kf, qf[h], st[f], 0, 0, 0);
            }
        }
        __builtin_amdgcn_s_setprio(0);

        // ---- scores (log2 units) + online softmax ----
        float sc[4][4];
        float tmf[4];
#pragma unroll
        for (int f = 0; f < 4; ++f) {
#pragma unroll
            for (int r = 0; r < 4; ++r) {
                const float sq = fmaxf(fmaf(-2.f, st[f][r], q2 + k2v[f][r]), 0.f);
                sc[f][r] = fmaf(-C2, fast_sqrt(sq), kcv[f][r]);
            }
            tmf[f] = fmaxf(fmaxf(sc[f][0], sc[f][1]), fmaxf(sc[f][2], sc[f][3]));
        }
        float tmax = fmaxf(fmaxf(tmf[0], tmf[1]), fmaxf(tmf[2], tmf[3]));
        tmax = fmaxf(tmax, __shfl_xor(tmax, 16));
        tmax = fmaxf(tmax, __shfl_xor(tmax, 32));
        // defer-max (T13): only rescale when max grows by > 8 nats
        if (tmax > m + THR2) {
            const float scale = fast_exp2(m - tmax);   // 0 on first tile
            m = tmax;
            lsA *= scale; lsB *= scale;
#pragma unroll
            for (int i = 0; i < 4; ++i) {
                ofr[i][0] *= scale; ofr[i][1] *= scale;
                ofr[i][2] *= scale; ofr[i][3] *= scale;
            }
        }
        // p = exp2(s~-m~) (bounded by 2^THR2), pack pairs, write per-wave P_lds
#pragma unroll
        for (int f = 0; f < 4; ++f) {
#pragma unroll
            for (int e = 0; e < 2; ++e) {
                const float p0 = fast_exp2(sc[f][2 * e]     - m);
                const float p1 = fast_exp2(sc[f][2 * e + 1] - m);
                lsA += p0; lsB += p1;
                const unsigned int pk = f2bf(p0) | (f2bf(p1) << 16);
                const int pr = 8 * f + 2 * g + e;
                const int wa = lq * 128 + pr * 4;
                *(unsigned int*)(Pw + (wa ^ swq)) = pk;
            }
        }

        // ---- PV (swapped): O^T[d][q] += V^T . P^T ----
        bf16x8 pf[2];
#pragma unroll
        for (int h = 0; h < 2; ++h) {
            const int ra = lq * 128 + h * 64 + g * 16;
            pf[h] = *(const bf16x8*)(Pw + (ra ^ swq));
        }
        __builtin_amdgcn_s_setprio(1);
#pragma unroll
        for (int db = 0; db < 4; ++db) {
#pragma unroll
            for (int h = 0; h < 2; ++h) {
                const int ra = (db * 16 + lq) * 128 + h * 64 + g * 16;
                bf16x8 vf = *(const bf16x8*)(Vt + (ra ^ swq));
                ofr[db] = __builtin_amdgcn_mfma_f32_16x16x32_bf16(vf, pf[h], ofr[db], 0, 0, 0);
            }
        }
        __builtin_amdgcn_s_setprio(0);

        __syncthreads();   // drains stage loads + all reads of buf[cur]
        cur ^= 1;
    }

    // ---- finalize ----
    float lsum = lsA + lsB;
    lsum += __shfl_xor(lsum, 16);
    lsum += __shfl_xor(lsum, 32);
    const float inv = 1.f / lsum;
    float* op = Og + hb + (size_t)q * DIM;
#pragma unroll
    for (int db = 0; db < 4; ++db) {
        f32x4 v;
#pragma unroll
        for (int r = 0; r < 4; ++r) v[r] = ofr[db][r] * inv;
        *(f32x4*)(op + db * 16 + g * 4) = v;   // d = 16*db + 4*g + r
    }
}

// ---------------- fallback (no-workspace monolithic) -------------------------
__global__ __launch_bounds__(256, 4)
void se_attn_mfma(const float* __restrict__ Qg, const float* __restrict__ Kg,
                  const float* __restrict__ Vg, float* __restrict__ Og) {
    __shared__ char  Kl[KVB * 128];
    __shared__ char  Vt[DIM * 128];
    __shared__ char  Pl[4][16 * 128];
    __shared__ float k2s[KVB];

    const int tid = threadIdx.x;
    const int w   = tid >> 6;
    const int l   = tid & 63;
    const int lq  = l & 15;
    const int g   = l >> 4;
    const size_t hb = (size_t)blockIdx.y * (SEQ * DIM);
    const int q = blockIdx.x * 64 + w * 16 + lq;
    char* Pw = Pl[w];
    const int swq = (lq & 7) << 4;

    bf16x8 qf[2];
    float q2 = 0.f;
#pragma unroll
    for (int h = 0; h < 2; ++h) {
        const float* qp = Qg + hb + (size_t)q * DIM + h * 32 + g * 8;
        f32x4 a = *(const f32x4*)qp;
        f32x4 b = *(const f32x4*)(qp + 4);
#pragma unroll
        for (int j = 0; j < 4; ++j) {
            q2 += a[j] * a[j] + b[j] * b[j];
            qf[h][j]     = (short)f2bf(a[j]);
            qf[h][4 + j] = (short)f2bf(b[j]);
        }
    }
    q2 += __shfl_xor(q2, 16);
    q2 += __shfl_xor(q2, 32);

    f32x4 ofr[4];
#pragma unroll
    for (int i = 0; i < 4; ++i) ofr[i] = (f32x4){0.f, 0.f, 0.f, 0.f};
    float m = -INFINITY, lsum = 0.f;

    const int srow = tid >> 2;
    const int sc4  = tid & 3;
    const int vpr  = tid & 31;
    const int vd0  = (tid >> 5) * 8;

    for (int kt = 0; kt < NKT; ++kt) {
        __syncthreads();
        {
            const float* kp = Kg + hb + (size_t)(kt * KVB + srow) * DIM + sc4 * 16;
            f32x4 a = *(const f32x4*)kp;
            f32x4 b = *(const f32x4*)(kp + 4);
            f32x4 c = *(const f32x4*)(kp + 8);
            f32x4 d = *(const f32x4*)(kp + 12);
            float part = 0.f;
#pragma unroll
            for (int j = 0; j < 4; ++j)
                part += a[j]*a[j] + b[j]*b[j] + c[j]*c[j] + d[j]*d[j];
            part += __shfl_xor(part, 1);
            part += __shfl_xor(part, 2);
            if (sc4 == 0) k2s[srow] = part;
            bf16x8 p0, p1;
#pragma unroll
            for (int j = 0; j < 4; ++j) {
                p0[j]     = (short)f2bf(a[j]);
                p0[4 + j] = (short)f2bf(b[j]);
                p1[j]     = (short)f2bf(c[j]);
                p1[4 + j] = (short)f2bf(d[j]);
            }
            const int sw = (srow & 7) << 4;
            const int wa = srow * 128 + sc4 * 32;
            *(bf16x8*)(Kl + (wa ^ sw))        = p0;
            *(bf16x8*)(Kl + ((wa + 16) ^ sw)) = p1;
        }
        {
            const float* vp = Vg + hb + (size_t)(kt * KVB + 2 * vpr) * DIM + vd0;
            f32x4 a0 = *(const f32x4*)vp;
            f32x4 a1 = *(const f32x4*)(vp + 4);
            f32x4 b0 = *(const f32x4*)(vp + DIM);
            f32x4 b1 = *(const f32x4*)(vp + DIM + 4);
#pragma unroll
            for (int j = 0; j < 8; ++j) {
                const float lo = (j < 4) ? a0[j] : a1[j - 4];
                const float hi = (j < 4) ? b0[j] : b1[j - 4];
                const unsigned int pk = f2bf(lo) | (f2bf(hi) << 16);
                const int d = vd0 + j;
                const int wa = d * 128 + vpr * 4;
                *(unsigned int*)(Vt + (wa ^ ((d & 7) << 4))) = pk;
            }
        }
        __syncthreads();

        f32x4 st[4];
#pragma unroll
        for (int f = 0; f < 4; ++f) st[f] = (f32x4){0.f, 0.f, 0.f, 0.f};
#pragma unroll
        for (int f = 0; f < 4; ++f) {
#pragma unroll
            for (int h = 0; h < 2; ++h) {
                const int ra = (f * 16 + lq) * 128 + h * 64 + g * 16;
                bf16x8 kf = *(const bf16x8*)(Kl + (ra ^ swq));
                st[f] = __builtin_amdgcn_mfma_f32_16x16x32_bf16(kf, qf[h], st[f], 0, 0, 0);
            }
        }

        float sc[4][4];
        float tmax = -INFINITY;
#pragma unroll
        for (int f = 0; f < 4; ++f) {
            const f32x4 k2v = *(const f32x4*)(k2s + f * 16 + g * 4);
#pragma unroll
            for (int r = 0; r < 4; ++r) {
                const float kk = k2v[r];
                const float sq = fmaxf(fmaf(-2.f, st[f][r], q2 + kk), 0.f);
                const float s  = (kk - sqrtf(sq)) * 0.0625f;
                sc[f][r] = s;
                tmax = fmaxf(tmax, s);
            }
        }
        tmax = fmaxf(tmax, __shfl_xor(tmax, 16));
        tmax = fmaxf(tmax, __shfl_xor(tmax, 32));
        const float nm    = fmaxf(m, tmax);
        const float scale = __expf(m - nm);
        m = nm;
        lsum *= scale;
#pragma unroll
        for (int i = 0; i < 4; ++i) {
            ofr[i][0] *= scale; ofr[i][1] *= scale;
            ofr[i][2] *= scale; ofr[i][3] *= scale;
        }
#pragma unroll
        for (int f = 0; f < 4; ++f) {
#pragma unroll
            for (int e = 0; e < 2; ++e) {
                const float p0 = __expf(sc[f][2 * e]     - m);
                const float p1 = __expf(sc[f][2 * e + 1] - m);
                lsum += p0 + p1;
                const unsigned int pk = f2bf(p0) | (f2bf(p1) << 16);
                const int pr = 8 * f + 2 * g + e;
                const int wa = lq * 128 + pr * 4;
                *(unsigned int*)(Pw + (wa ^ swq)) = pk;
            }
        }

        bf16x8 pf[2];
#pragma unroll
        for (int h = 0; h < 2; ++h) {
            const int ra = lq * 128 + h * 64 + g * 16;
            pf[h] = *(const bf16x8*)(Pw + (ra ^ swq));
        }
#pragma unroll
        for (int db = 0; db < 4; ++db) {
#pragma unroll
            for (int h = 0; h < 2; ++h) {
                const int ra = (db * 16 + lq) * 128 + h * 64 + g * 16;
                bf16x8 vf = *(const bf16x8*)(Vt + (ra ^ swq));
                ofr[db] = __builtin_amdgcn_mfma_f32_16x16x32_bf16(vf, pf[h], ofr[db], 0, 0, 0);
            }
        }
    }

    lsum += __shfl_xor(lsum, 16);
    lsum += __shfl_xor(lsum, 32);
    const float inv = 1.f / lsum;
    float* op = Og + hb + (size_t)q * DIM;
#pragma unroll
    for (int db = 0; db < 4; ++db) {
#pragma unroll
        for (int r = 0; r < 4; ++r) {
            op[db * 16 + g * 4 + r] = ofr[db][r] * inv;
        }
    }
}

extern "C" void kernel_launch(void* const* d_in, const int* in_sizes, int n_in,
                              void* d_out, int out_size, void* d_ws, size_t ws_size,
                              hipStream_t stream) {
    const float* Q = (const float*)d_in[0];
    const float* K = (const float*)d_in[1];
    const float* V = (const float*)d_in[2];
    float* O = (float*)d_out;

    const size_t KP_B = (size_t)NHEAD * NKT * TILE_B;    // 8 MB
    const size_t K2_B = (size_t)NHEAD * SEQ * 4;         // 256 KB
    const size_t need = 2 * KP_B + 2 * K2_B;

    if (ws_size >= need) {
        char*  Kp  = (char*)d_ws;
        char*  Vp  = Kp + KP_B;
        float* k2  = (float*)(Kp + 2 * KP_B);
        float* k2c = (float*)((char*)k2 + K2_B);
        prep_kv<<<dim3(NKT, NHEAD), 256, 0, stream>>>(K, V, Kp, Vp, k2, k2c);
        se_attn_main<<<dim3(SEQ / QBLK, NHEAD), 512, 0, stream>>>(Q, Kp, Vp, k2, k2c, O);
    } else {
        se_attn_mfma<<<dim3(SEQ / 64, NHEAD), 256, 0, stream>>>(Q, K, V, O);
    }
}